// Round 5
// baseline (302.496 us; speedup 1.0000x reference)
//
#include <hip/hip_runtime.h>

#define N_NODES 50000
#define N_EDGES 800000
#define F_IN   128
#define F_MID  64
#define F_OUT  40
#define SCAN_B 196   // ceil(N_NODES/256) blocks for the hierarchical scan

// ---------------- degree ----------------

__global__ __launch_bounds__(256) void deg_kernel(const int* __restrict__ ei, int* __restrict__ deg) {
    int e = blockIdx.x * 256 + threadIdx.x;
    if (e < N_EDGES) atomicAdd(&deg[ei[N_EDGES + e]], 1);   // col = target
}

// ---------------- hierarchical exclusive scan of deg -> rowptr/cursor (+dinv) ----------------

__global__ __launch_bounds__(256) void bsum_kernel(const int* __restrict__ deg, int* __restrict__ bsum) {
    int idx = blockIdx.x * 256 + threadIdx.x;
    int v = (idx < N_NODES) ? deg[idx] : 0;
#pragma unroll
    for (int off = 32; off > 0; off >>= 1) v += __shfl_xor(v, off, 64);
    __shared__ int ws[4];
    if ((threadIdx.x & 63) == 0) ws[threadIdx.x >> 6] = v;
    __syncthreads();
    if (threadIdx.x == 0) bsum[blockIdx.x] = ws[0] + ws[1] + ws[2] + ws[3];
}

__global__ __launch_bounds__(256) void bscan_kernel(const int* __restrict__ bsum, int* __restrict__ boff) {
    int tid = threadIdx.x;
    int lane = tid & 63, wv = tid >> 6;
    int v = (tid < SCAN_B) ? bsum[tid] : 0;
    int inc = v;
#pragma unroll
    for (int s = 1; s < 64; s <<= 1) {
        int t = __shfl_up(inc, s, 64);
        if (lane >= s) inc += t;
    }
    __shared__ int ws[4];
    if (lane == 63) ws[wv] = inc;
    __syncthreads();
    int woff = 0;
    for (int w = 0; w < wv; ++w) woff += ws[w];
    if (tid < SCAN_B) boff[tid] = woff + inc - v;   // exclusive prefix of block sums
}

__global__ __launch_bounds__(256) void bscan2_kernel(const int* __restrict__ deg,
                                                     const int* __restrict__ boff,
                                                     int* __restrict__ rowptr,
                                                     int* __restrict__ cursor,
                                                     float* __restrict__ dinv) {
    int idx = blockIdx.x * 256 + threadIdx.x;
    int lane = threadIdx.x & 63, wv = threadIdx.x >> 6;
    int v = (idx < N_NODES) ? deg[idx] : 0;
    int inc = v;
#pragma unroll
    for (int s = 1; s < 64; s <<= 1) {
        int t = __shfl_up(inc, s, 64);
        if (lane >= s) inc += t;
    }
    __shared__ int ws[4];
    if (lane == 63) ws[wv] = inc;
    __syncthreads();
    int off = boff[blockIdx.x];
    for (int w = 0; w < wv; ++w) off += ws[w];
    int ex = off + inc - v;
    if (idx < N_NODES) {
        rowptr[idx] = ex;
        cursor[idx] = ex;
        dinv[idx]   = rsqrtf((float)v + 1.0f);   // +1 = self loop
    }
    if (idx == N_NODES - 1) rowptr[N_NODES] = ex + v;   // == N_EDGES
}

// ---------------- CSR fill: group edges by destination (src index only, 4 B/edge) ----------------

__global__ __launch_bounds__(256) void fill_kernel(const int* __restrict__ ei,
                                                   int* __restrict__ cursor,
                                                   int* __restrict__ srcs) {
    int e = blockIdx.x * 256 + threadIdx.x;
    if (e >= N_EDGES) return;
    int r = ei[e];
    int c = ei[N_EDGES + e];
    int pos = atomicAdd(&cursor[c], 1);
    srcs[pos] = r;
}

// ---------------- GEMM1: hw1 = x @ W1  (128 -> 64) ----------------
// 64 rows x 64 cols per block; 256 threads; 4x4 register tile per thread.

__global__ __launch_bounds__(256) void gemm1_kernel(const float* __restrict__ x,
                                                    const float* __restrict__ W1,
                                                    float* __restrict__ hw1) {
    __shared__ float sW[F_IN * F_MID];   // 32 KB, row-major [k][c]
    __shared__ float sX[64][68];         // 17 KB, one K-half, padded
    int tid = threadIdx.x;
    const float4* W4 = (const float4*)W1;
    float4* sW4 = (float4*)sW;
    for (int i = tid; i < F_IN * F_MID / 4; i += 256) sW4[i] = W4[i];

    int row0 = blockIdx.x * 64;
    int tx = tid & 15, ty = tid >> 4;
    int c0 = tx * 4, r0 = ty * 4;
    float acc[4][4] = {};

    for (int p = 0; p < 2; ++p) {
        __syncthreads();
#pragma unroll
        for (int it = 0; it < 4; ++it) {
            int i = (tid + it * 256) * 4;      // element index in 64x64 tile
            int r = i >> 6, k = i & 63;
            float4 v = make_float4(0.f, 0.f, 0.f, 0.f);
            if (row0 + r < N_NODES)
                v = *(const float4*)&x[(size_t)(row0 + r) * F_IN + p * 64 + k];
            *(float4*)&sX[r][k] = v;
        }
        __syncthreads();
        const float* sWp = sW + p * 64 * F_MID;
#pragma unroll 4
        for (int k = 0; k < 64; ++k) {
            float4 w = *(const float4*)&sWp[k * F_MID + c0];
            float a0 = sX[r0 + 0][k];
            float a1 = sX[r0 + 1][k];
            float a2 = sX[r0 + 2][k];
            float a3 = sX[r0 + 3][k];
            acc[0][0] = fmaf(a0, w.x, acc[0][0]); acc[0][1] = fmaf(a0, w.y, acc[0][1]);
            acc[0][2] = fmaf(a0, w.z, acc[0][2]); acc[0][3] = fmaf(a0, w.w, acc[0][3]);
            acc[1][0] = fmaf(a1, w.x, acc[1][0]); acc[1][1] = fmaf(a1, w.y, acc[1][1]);
            acc[1][2] = fmaf(a1, w.z, acc[1][2]); acc[1][3] = fmaf(a1, w.w, acc[1][3]);
            acc[2][0] = fmaf(a2, w.x, acc[2][0]); acc[2][1] = fmaf(a2, w.y, acc[2][1]);
            acc[2][2] = fmaf(a2, w.z, acc[2][2]); acc[2][3] = fmaf(a2, w.w, acc[2][3]);
            acc[3][0] = fmaf(a3, w.x, acc[3][0]); acc[3][1] = fmaf(a3, w.y, acc[3][1]);
            acc[3][2] = fmaf(a3, w.z, acc[3][2]); acc[3][3] = fmaf(a3, w.w, acc[3][3]);
        }
    }
#pragma unroll
    for (int j = 0; j < 4; ++j) {
        int row = row0 + r0 + j;
        if (row < N_NODES) {
            float4 o = make_float4(acc[j][0], acc[j][1], acc[j][2], acc[j][3]);
            *(float4*)&hw1[(size_t)row * F_MID + c0] = o;
        }
    }
}

// ---------------- gather1 + self-loop + bias + ReLU + fused GEMM2 ----------------
// one wave per node, lane = feature. After computing the h-row (one feature per
// lane), the wave computes hw2-row in place via shuffle-broadcast of h[k]
// against LDS-staged W2 — no block sync inside divergent code.

__global__ __launch_bounds__(256) void gather1_gemm2_kernel(const int* __restrict__ rowptr,
                                                            const int* __restrict__ srcs,
                                                            const float* __restrict__ hw1,
                                                            const float* __restrict__ dinv,
                                                            const float* __restrict__ b1,
                                                            const float* __restrict__ W2,
                                                            float* __restrict__ hw2) {
    __shared__ float sW2[F_MID * F_OUT];   // 10 KB
    for (int i = threadIdx.x; i < F_MID * F_OUT; i += 256) sW2[i] = W2[i];
    __syncthreads();

    int n = blockIdx.x * 4 + (threadIdx.x >> 6);
    int lane = threadIdx.x & 63;
    if (n >= N_NODES) return;
    int s = rowptr[n], e = rowptr[n + 1];
    float acc = 0.f;
    for (int base = s; base < e; base += 64) {
        int cnt = e - base; if (cnt > 64) cnt = 64;
        int   ms = (lane < cnt) ? srcs[base + lane] : 0;
        float mw = (lane < cnt) ? dinv[ms] : 0.f;
        int j = 0;
        for (; j + 4 <= cnt; j += 4) {
            int i0 = __shfl(ms, j, 64),     i1 = __shfl(ms, j + 1, 64);
            int i2 = __shfl(ms, j + 2, 64), i3 = __shfl(ms, j + 3, 64);
            float w0 = __shfl(mw, j, 64),     w1 = __shfl(mw, j + 1, 64);
            float w2 = __shfl(mw, j + 2, 64), w3 = __shfl(mw, j + 3, 64);
            float v0 = hw1[(size_t)i0 * F_MID + lane];
            float v1 = hw1[(size_t)i1 * F_MID + lane];
            float v2 = hw1[(size_t)i2 * F_MID + lane];
            float v3 = hw1[(size_t)i3 * F_MID + lane];
            acc = fmaf(w0, v0, acc); acc = fmaf(w1, v1, acc);
            acc = fmaf(w2, v2, acc); acc = fmaf(w3, v3, acc);
        }
        for (; j < cnt; ++j) {
            int i0 = __shfl(ms, j, 64);
            float w0 = __shfl(mw, j, 64);
            acc = fmaf(w0, hw1[(size_t)i0 * F_MID + lane], acc);
        }
    }
    float d = dinv[n];
    float hv = fmaf(acc, d, hw1[(size_t)n * F_MID + lane] * d * d) + b1[lane];
    hv = fmaxf(hv, 0.f);                     // h[n][lane], held in-register

    // fused gemm2: o[c] = sum_k h[k] * W2[k][c];  h[k] broadcast via shfl
    int cc = (lane < F_OUT) ? lane : 0;      // safe LDS column for idle lanes
    float o = 0.f;
#pragma unroll 8
    for (int k = 0; k < F_MID; ++k) {
        float hk = __shfl(hv, k, 64);        // all 64 lanes participate
        o = fmaf(hk, sW2[k * F_OUT + cc], o);
    }
    if (lane < F_OUT) hw2[(size_t)n * F_OUT + lane] = o;
}

// ---------------- gather2 + self-loop + bias + softmax ----------------

__global__ __launch_bounds__(256) void gather2_softmax_kernel(const int* __restrict__ rowptr,
                                                              const int* __restrict__ srcs,
                                                              const float* __restrict__ hw2,
                                                              const float* __restrict__ dinv,
                                                              const float* __restrict__ b2,
                                                              float* __restrict__ out) {
    int n = blockIdx.x * 4 + (threadIdx.x >> 6);
    int lane = threadIdx.x & 63;
    if (n >= N_NODES) return;
    int s = rowptr[n], e = rowptr[n + 1];
    float acc = 0.f;
    for (int base = s; base < e; base += 64) {
        int cnt = e - base; if (cnt > 64) cnt = 64;
        int   ms = (lane < cnt) ? srcs[base + lane] : 0;
        float mw = (lane < cnt) ? dinv[ms] : 0.f;
        int j = 0;
        for (; j + 4 <= cnt; j += 4) {
            int i0 = __shfl(ms, j, 64),     i1 = __shfl(ms, j + 1, 64);
            int i2 = __shfl(ms, j + 2, 64), i3 = __shfl(ms, j + 3, 64);
            float w0 = __shfl(mw, j, 64),     w1 = __shfl(mw, j + 1, 64);
            float w2 = __shfl(mw, j + 2, 64), w3 = __shfl(mw, j + 3, 64);
            if (lane < F_OUT) {
                float v0 = hw2[(size_t)i0 * F_OUT + lane];
                float v1 = hw2[(size_t)i1 * F_OUT + lane];
                float v2 = hw2[(size_t)i2 * F_OUT + lane];
                float v3 = hw2[(size_t)i3 * F_OUT + lane];
                acc = fmaf(w0, v0, acc); acc = fmaf(w1, v1, acc);
                acc = fmaf(w2, v2, acc); acc = fmaf(w3, v3, acc);
            }
        }
        for (; j < cnt; ++j) {
            int i0 = __shfl(ms, j, 64);
            float w0 = __shfl(mw, j, 64);
            if (lane < F_OUT) acc = fmaf(w0, hw2[(size_t)i0 * F_OUT + lane], acc);
        }
    }
    float d = dinv[n];
    float v = -3.402823466e38f;
    if (lane < F_OUT)
        v = fmaf(acc, d, hw2[(size_t)n * F_OUT + lane] * d * d) + b2[lane];
    float m = v;
#pragma unroll
    for (int off = 32; off > 0; off >>= 1) m = fmaxf(m, __shfl_xor(m, off, 64));
    float p = (lane < F_OUT) ? __expf(v - m) : 0.f;
    float su = p;
#pragma unroll
    for (int off = 32; off > 0; off >>= 1) su += __shfl_xor(su, off, 64);
    if (lane < F_OUT) out[(size_t)n * F_OUT + lane] = p / su;
}

// ---------------- launch ----------------

extern "C" void kernel_launch(void* const* d_in, const int* in_sizes, int n_in,
                              void* d_out, int out_size, void* d_ws, size_t ws_size,
                              hipStream_t stream) {
    const float* x  = (const float*)d_in[0];
    const int*   ei = (const int*)d_in[1];
    const float* W1 = (const float*)d_in[2];
    const float* b1 = (const float*)d_in[3];
    const float* W2 = (const float*)d_in[4];
    const float* b2 = (const float*)d_in[5];
    float* out = (float*)d_out;

    char* ws = (char*)d_ws;
    size_t off = 0;
    auto alloc = [&](size_t bytes) -> void* {
        void* p = ws + off;
        off += (bytes + 255) & ~(size_t)255;
        return p;
    };
    int*   deg    = (int*)  alloc(N_NODES * sizeof(int));
    float* dinv   = (float*)alloc(N_NODES * sizeof(float));
    int*   rowptr = (int*)  alloc((N_NODES + 1) * sizeof(int));
    int*   cursor = (int*)  alloc(N_NODES * sizeof(int));
    int*   bsum   = (int*)  alloc(SCAN_B * sizeof(int));
    int*   boff   = (int*)  alloc(SCAN_B * sizeof(int));
    int*   srcs   = (int*)  alloc((size_t)N_EDGES * sizeof(int));
    float* hw1    = (float*)alloc((size_t)N_NODES * F_MID * sizeof(float));
    float* hw2    = (float*)alloc((size_t)N_NODES * F_OUT * sizeof(float));

    hipMemsetAsync(deg, 0, N_NODES * sizeof(int), stream);

    deg_kernel   <<<(N_EDGES + 255) / 256, 256, 0, stream>>>(ei, deg);
    bsum_kernel  <<<SCAN_B, 256, 0, stream>>>(deg, bsum);
    bscan_kernel <<<1, 256, 0, stream>>>(bsum, boff);
    bscan2_kernel<<<SCAN_B, 256, 0, stream>>>(deg, boff, rowptr, cursor, dinv);
    fill_kernel  <<<(N_EDGES + 255) / 256, 256, 0, stream>>>(ei, cursor, srcs);
    gemm1_kernel <<<(N_NODES + 63) / 64, 256, 0, stream>>>(x, W1, hw1);
    gather1_gemm2_kernel<<<(N_NODES + 3) / 4, 256, 0, stream>>>(rowptr, srcs, hw1, dinv, b1, W2, hw2);
    gather2_softmax_kernel<<<(N_NODES + 3) / 4, 256, 0, stream>>>(rowptr, srcs, hw2, dinv, b2, out);
}

// Round 6
// 283.150 us; speedup vs baseline: 1.0683x; 1.0683x over previous
//
#include <hip/hip_runtime.h>

#define N_NODES 50000
#define N_EDGES 800000
#define F_IN   128
#define F_MID  64
#define F_OUT  40
#define SCAN_B 196   // ceil(N_NODES/256) blocks for the hierarchical scan

// ---------------- degree ----------------

__global__ __launch_bounds__(256) void deg_kernel(const int* __restrict__ ei, int* __restrict__ deg) {
    int e = blockIdx.x * 256 + threadIdx.x;
    if (e < N_EDGES) atomicAdd(&deg[ei[N_EDGES + e]], 1);   // col = target
}

// ---------------- hierarchical exclusive scan of deg -> rowptr/cursor (+dinv) ----------------

__global__ __launch_bounds__(256) void bsum_kernel(const int* __restrict__ deg, int* __restrict__ bsum) {
    int idx = blockIdx.x * 256 + threadIdx.x;
    int v = (idx < N_NODES) ? deg[idx] : 0;
#pragma unroll
    for (int off = 32; off > 0; off >>= 1) v += __shfl_xor(v, off, 64);
    __shared__ int ws[4];
    if ((threadIdx.x & 63) == 0) ws[threadIdx.x >> 6] = v;
    __syncthreads();
    if (threadIdx.x == 0) bsum[blockIdx.x] = ws[0] + ws[1] + ws[2] + ws[3];
}

__global__ __launch_bounds__(256) void bscan_kernel(const int* __restrict__ bsum, int* __restrict__ boff) {
    int tid = threadIdx.x;
    int lane = tid & 63, wv = tid >> 6;
    int v = (tid < SCAN_B) ? bsum[tid] : 0;
    int inc = v;
#pragma unroll
    for (int s = 1; s < 64; s <<= 1) {
        int t = __shfl_up(inc, s, 64);
        if (lane >= s) inc += t;
    }
    __shared__ int ws[4];
    if (lane == 63) ws[wv] = inc;
    __syncthreads();
    int woff = 0;
    for (int w = 0; w < wv; ++w) woff += ws[w];
    if (tid < SCAN_B) boff[tid] = woff + inc - v;   // exclusive prefix of block sums
}

__global__ __launch_bounds__(256) void bscan2_kernel(const int* __restrict__ deg,
                                                     const int* __restrict__ boff,
                                                     int* __restrict__ rowptr,
                                                     int* __restrict__ cursor,
                                                     float* __restrict__ dinv) {
    int idx = blockIdx.x * 256 + threadIdx.x;
    int lane = threadIdx.x & 63, wv = threadIdx.x >> 6;
    int v = (idx < N_NODES) ? deg[idx] : 0;
    int inc = v;
#pragma unroll
    for (int s = 1; s < 64; s <<= 1) {
        int t = __shfl_up(inc, s, 64);
        if (lane >= s) inc += t;
    }
    __shared__ int ws[4];
    if (lane == 63) ws[wv] = inc;
    __syncthreads();
    int off = boff[blockIdx.x];
    for (int w = 0; w < wv; ++w) off += ws[w];
    int ex = off + inc - v;
    if (idx < N_NODES) {
        rowptr[idx] = ex;
        cursor[idx] = ex;
        dinv[idx]   = rsqrtf((float)v + 1.0f);   // +1 = self loop
    }
    if (idx == N_NODES - 1) rowptr[N_NODES] = ex + v;   // == N_EDGES
}

// ---------------- CSR fill: group edges by destination (src index only, 4 B/edge) ----------------

__global__ __launch_bounds__(256) void fill_kernel(const int* __restrict__ ei,
                                                   int* __restrict__ cursor,
                                                   int* __restrict__ srcs) {
    int e = blockIdx.x * 256 + threadIdx.x;
    if (e >= N_EDGES) return;
    int r = ei[e];
    int c = ei[N_EDGES + e];
    int pos = atomicAdd(&cursor[c], 1);
    srcs[pos] = r;
}

// ---------------- GEMM1: hw1s = (x @ W1) * dinv[row]  (128 -> 64, pre-scaled) ----------------
// 64 rows x 64 cols per block; 256 threads; 4x4 register tile per thread.
// Pre-scaling by dinv[row] folds the per-edge weight dinv[src] into the message
// rows, so the gather kernels do pure row sums (no weight loads/shuffles).

__global__ __launch_bounds__(256) void gemm1_kernel(const float* __restrict__ x,
                                                    const float* __restrict__ W1,
                                                    const float* __restrict__ dinv,
                                                    float* __restrict__ hw1s) {
    __shared__ float sW[F_IN * F_MID];   // 32 KB, row-major [k][c]
    __shared__ float sX[64][68];         // 17 KB, one K-half, padded
    int tid = threadIdx.x;
    const float4* W4 = (const float4*)W1;
    float4* sW4 = (float4*)sW;
    for (int i = tid; i < F_IN * F_MID / 4; i += 256) sW4[i] = W4[i];

    int row0 = blockIdx.x * 64;
    int tx = tid & 15, ty = tid >> 4;
    int c0 = tx * 4, r0 = ty * 4;
    float acc[4][4] = {};

    for (int p = 0; p < 2; ++p) {
        __syncthreads();
#pragma unroll
        for (int it = 0; it < 4; ++it) {
            int i = (tid + it * 256) * 4;      // element index in 64x64 tile
            int r = i >> 6, k = i & 63;
            float4 v = make_float4(0.f, 0.f, 0.f, 0.f);
            if (row0 + r < N_NODES)
                v = *(const float4*)&x[(size_t)(row0 + r) * F_IN + p * 64 + k];
            *(float4*)&sX[r][k] = v;
        }
        __syncthreads();
        const float* sWp = sW + p * 64 * F_MID;
#pragma unroll 4
        for (int k = 0; k < 64; ++k) {
            float4 w = *(const float4*)&sWp[k * F_MID + c0];
            float a0 = sX[r0 + 0][k];
            float a1 = sX[r0 + 1][k];
            float a2 = sX[r0 + 2][k];
            float a3 = sX[r0 + 3][k];
            acc[0][0] = fmaf(a0, w.x, acc[0][0]); acc[0][1] = fmaf(a0, w.y, acc[0][1]);
            acc[0][2] = fmaf(a0, w.z, acc[0][2]); acc[0][3] = fmaf(a0, w.w, acc[0][3]);
            acc[1][0] = fmaf(a1, w.x, acc[1][0]); acc[1][1] = fmaf(a1, w.y, acc[1][1]);
            acc[1][2] = fmaf(a1, w.z, acc[1][2]); acc[1][3] = fmaf(a1, w.w, acc[1][3]);
            acc[2][0] = fmaf(a2, w.x, acc[2][0]); acc[2][1] = fmaf(a2, w.y, acc[2][1]);
            acc[2][2] = fmaf(a2, w.z, acc[2][2]); acc[2][3] = fmaf(a2, w.w, acc[2][3]);
            acc[3][0] = fmaf(a3, w.x, acc[3][0]); acc[3][1] = fmaf(a3, w.y, acc[3][1]);
            acc[3][2] = fmaf(a3, w.z, acc[3][2]); acc[3][3] = fmaf(a3, w.w, acc[3][3]);
        }
    }
#pragma unroll
    for (int j = 0; j < 4; ++j) {
        int row = row0 + r0 + j;
        if (row < N_NODES) {
            float d = dinv[row];
            float4 o = make_float4(acc[j][0] * d, acc[j][1] * d, acc[j][2] * d, acc[j][3] * d);
            *(float4*)&hw1s[(size_t)row * F_MID + c0] = o;
        }
    }
}

// ---------------- gather1: h = relu(dinv[n]*(sum_e hw1s[src] + hw1s[n]) + b1) ----------------
// one wave per node, lane = feature; index-only shuffles, pure adds.

__global__ __launch_bounds__(256) void gather1_kernel(const int* __restrict__ rowptr,
                                                      const int* __restrict__ srcs,
                                                      const float* __restrict__ hw1s,
                                                      const float* __restrict__ dinv,
                                                      const float* __restrict__ b1,
                                                      float* __restrict__ h) {
    int n = blockIdx.x * 4 + (threadIdx.x >> 6);
    int lane = threadIdx.x & 63;
    if (n >= N_NODES) return;
    int s = rowptr[n], e = rowptr[n + 1];
    float acc = 0.f;
    for (int base = s; base < e; base += 64) {
        int cnt = e - base; if (cnt > 64) cnt = 64;
        int ms = (lane < cnt) ? srcs[base + lane] : 0;
        int j = 0;
        for (; j + 4 <= cnt; j += 4) {
            int i0 = __shfl(ms, j, 64),     i1 = __shfl(ms, j + 1, 64);
            int i2 = __shfl(ms, j + 2, 64), i3 = __shfl(ms, j + 3, 64);
            float v0 = hw1s[(size_t)i0 * F_MID + lane];
            float v1 = hw1s[(size_t)i1 * F_MID + lane];
            float v2 = hw1s[(size_t)i2 * F_MID + lane];
            float v3 = hw1s[(size_t)i3 * F_MID + lane];
            acc += v0 + v1 + v2 + v3;
        }
        for (; j < cnt; ++j) {
            int i0 = __shfl(ms, j, 64);
            acc += hw1s[(size_t)i0 * F_MID + lane];
        }
    }
    float d = dinv[n];
    float v = fmaf(d, acc + hw1s[(size_t)n * F_MID + lane], b1[lane]);
    h[(size_t)n * F_MID + lane] = fmaxf(v, 0.f);
}

// ---------------- GEMM2: hw2s = (h @ W2) * dinv[row]  (64 -> 40, pre-scaled) ----------------

__global__ __launch_bounds__(256) void gemm2_kernel(const float* __restrict__ h,
                                                    const float* __restrict__ W2,
                                                    const float* __restrict__ dinv,
                                                    float* __restrict__ hw2s) {
    __shared__ float sW[F_MID * F_OUT];  // 10 KB
    for (int i = threadIdx.x; i < F_MID * F_OUT; i += 256) sW[i] = W2[i];
    __syncthreads();
    int idx = blockIdx.x * 256 + threadIdx.x;
    if (idx >= N_NODES * F_OUT) return;
    int r = idx / F_OUT;
    int c = idx % F_OUT;
    float acc = 0.f;
#pragma unroll
    for (int k = 0; k < F_MID; ++k) acc = fmaf(h[(size_t)r * F_MID + k], sW[k * F_OUT + c], acc);
    hw2s[idx] = acc * dinv[r];
}

// ---------------- gather2 + softmax: out = softmax(dinv[n]*(sum_e hw2s[src] + hw2s[n]) + b2) ----------------

__global__ __launch_bounds__(256) void gather2_softmax_kernel(const int* __restrict__ rowptr,
                                                              const int* __restrict__ srcs,
                                                              const float* __restrict__ hw2s,
                                                              const float* __restrict__ dinv,
                                                              const float* __restrict__ b2,
                                                              float* __restrict__ out) {
    int n = blockIdx.x * 4 + (threadIdx.x >> 6);
    int lane = threadIdx.x & 63;
    if (n >= N_NODES) return;
    int s = rowptr[n], e = rowptr[n + 1];
    float acc = 0.f;
    for (int base = s; base < e; base += 64) {
        int cnt = e - base; if (cnt > 64) cnt = 64;
        int ms = (lane < cnt) ? srcs[base + lane] : 0;
        int j = 0;
        for (; j + 4 <= cnt; j += 4) {
            int i0 = __shfl(ms, j, 64),     i1 = __shfl(ms, j + 1, 64);
            int i2 = __shfl(ms, j + 2, 64), i3 = __shfl(ms, j + 3, 64);
            if (lane < F_OUT) {
                float v0 = hw2s[(size_t)i0 * F_OUT + lane];
                float v1 = hw2s[(size_t)i1 * F_OUT + lane];
                float v2 = hw2s[(size_t)i2 * F_OUT + lane];
                float v3 = hw2s[(size_t)i3 * F_OUT + lane];
                acc += v0 + v1 + v2 + v3;
            }
        }
        for (; j < cnt; ++j) {
            int i0 = __shfl(ms, j, 64);
            if (lane < F_OUT) acc += hw2s[(size_t)i0 * F_OUT + lane];
        }
    }
    float d = dinv[n];
    float v = -3.402823466e38f;
    if (lane < F_OUT)
        v = fmaf(d, acc + hw2s[(size_t)n * F_OUT + lane], b2[lane]);
    float m = v;
#pragma unroll
    for (int off = 32; off > 0; off >>= 1) m = fmaxf(m, __shfl_xor(m, off, 64));
    float p = (lane < F_OUT) ? __expf(v - m) : 0.f;
    float su = p;
#pragma unroll
    for (int off = 32; off > 0; off >>= 1) su += __shfl_xor(su, off, 64);
    if (lane < F_OUT) out[(size_t)n * F_OUT + lane] = p / su;
}

// ---------------- launch ----------------

extern "C" void kernel_launch(void* const* d_in, const int* in_sizes, int n_in,
                              void* d_out, int out_size, void* d_ws, size_t ws_size,
                              hipStream_t stream) {
    const float* x  = (const float*)d_in[0];
    const int*   ei = (const int*)d_in[1];
    const float* W1 = (const float*)d_in[2];
    const float* b1 = (const float*)d_in[3];
    const float* W2 = (const float*)d_in[4];
    const float* b2 = (const float*)d_in[5];
    float* out = (float*)d_out;

    char* ws = (char*)d_ws;
    size_t off = 0;
    auto alloc = [&](size_t bytes) -> void* {
        void* p = ws + off;
        off += (bytes + 255) & ~(size_t)255;
        return p;
    };
    int*   deg    = (int*)  alloc(N_NODES * sizeof(int));
    float* dinv   = (float*)alloc(N_NODES * sizeof(float));
    int*   rowptr = (int*)  alloc((N_NODES + 1) * sizeof(int));
    int*   cursor = (int*)  alloc(N_NODES * sizeof(int));
    int*   bsum   = (int*)  alloc(SCAN_B * sizeof(int));
    int*   boff   = (int*)  alloc(SCAN_B * sizeof(int));
    int*   srcs   = (int*)  alloc((size_t)N_EDGES * sizeof(int));
    float* hw1s   = (float*)alloc((size_t)N_NODES * F_MID * sizeof(float));
    float* h      = (float*)alloc((size_t)N_NODES * F_MID * sizeof(float));
    float* hw2s   = (float*)alloc((size_t)N_NODES * F_OUT * sizeof(float));

    hipMemsetAsync(deg, 0, N_NODES * sizeof(int), stream);

    deg_kernel   <<<(N_EDGES + 255) / 256, 256, 0, stream>>>(ei, deg);
    bsum_kernel  <<<SCAN_B, 256, 0, stream>>>(deg, bsum);
    bscan_kernel <<<1, 256, 0, stream>>>(bsum, boff);
    bscan2_kernel<<<SCAN_B, 256, 0, stream>>>(deg, boff, rowptr, cursor, dinv);
    fill_kernel  <<<(N_EDGES + 255) / 256, 256, 0, stream>>>(ei, cursor, srcs);
    gemm1_kernel <<<(N_NODES + 63) / 64, 256, 0, stream>>>(x, W1, dinv, hw1s);
    gather1_kernel<<<(N_NODES + 3) / 4, 256, 0, stream>>>(rowptr, srcs, hw1s, dinv, b1, h);
    gemm2_kernel <<<(N_NODES * F_OUT + 255) / 256, 256, 0, stream>>>(h, W2, dinv, hw2s);
    gather2_softmax_kernel<<<(N_NODES + 3) / 4, 256, 0, stream>>>(rowptr, srcs, hw2s, dinv, b2, out);
}